// Round 1
// baseline (1222.857 us; speedup 1.0000x reference)
//
#include <hip/hip_runtime.h>
#include <math.h>

#define D 64
#define DH 32

// ---------------------------------------------------------------------------
// Kernel 1: mark nodes that appear as a source (row) of at least one edge.
// Softmax over each row-segment sums to exactly 1, so out[i] = h[i]*(1+peak)+bias
// iff node i has an outgoing edge, else out[i] = bias.
// ---------------------------------------------------------------------------
__global__ void edge_flag_kernel(const int* __restrict__ row, int* __restrict__ flag, int E) {
    int e = blockIdx.x * blockDim.x + threadIdx.x;
    if (e < E) flag[row[e]] = 1;
}

__device__ __forceinline__ float gelu_exact(float v) {
    return 0.5f * v * (1.0f + erff(v * 0.70710678118654752f));
}

// ---------------------------------------------------------------------------
// Kernel 2: fused  h = x@W_lin ; peak = sigmoid(gelu(h@W1+b1)@W2+b2) ;
//           out = (flag ? h*(1+peak) : 0) + bias
// One thread per node. Weights staged in LDS (uniform broadcast reads).
// h[16] float4 and t[8] float4 in registers, all statically indexed.
// ---------------------------------------------------------------------------
__global__ __launch_bounds__(128) void gat_fused(
    const float* __restrict__ x, const float* __restrict__ Wlin,
    const float* __restrict__ bias, const float* __restrict__ W1,
    const float* __restrict__ b1, const float* __restrict__ W2,
    const float* __restrict__ b2, const int* __restrict__ flag,
    float* __restrict__ out, int N)
{
    __shared__ float sW[D][D];    // 16 KB
    __shared__ float sW1[D][DH];  // 8 KB
    __shared__ float sb1[DH];
    __shared__ float sW2[DH];
    __shared__ float sbias[D];
    __shared__ float sb2;

    const int tid = threadIdx.x;
    // stage weights (vectorized, coalesced)
    {
        float4* dW = (float4*)sW;
        const float4* gW = (const float4*)Wlin;
        for (int idx = tid; idx < D * D / 4; idx += blockDim.x) dW[idx] = gW[idx];
        float4* dW1 = (float4*)sW1;
        const float4* gW1 = (const float4*)W1;
        for (int idx = tid; idx < D * DH / 4; idx += blockDim.x) dW1[idx] = gW1[idx];
        if (tid < DH) { sb1[tid] = b1[tid]; sW2[tid] = W2[tid]; }
        if (tid < D)  { sbias[tid] = bias[tid]; }
        if (tid == 0) { sb2 = b2[0]; }
    }
    __syncthreads();

    const int i = blockIdx.x * blockDim.x + tid;
    if (i >= N) return;

    const float4* xr = (const float4*)(x + (size_t)i * D);

    // ---- h = x[i] @ W_lin  (64x64) ----
    float4 h[16];
#pragma unroll
    for (int jj = 0; jj < 16; ++jj) h[jj] = make_float4(0.f, 0.f, 0.f, 0.f);

    for (int c = 0; c < 4; ++c) {     // rolled: keeps I-cache small
        float4 xv[4];
        xv[0] = xr[4 * c + 0];
        xv[1] = xr[4 * c + 1];
        xv[2] = xr[4 * c + 2];
        xv[3] = xr[4 * c + 3];
#pragma unroll
        for (int q = 0; q < 4; ++q) {
#pragma unroll
            for (int k4 = 0; k4 < 4; ++k4) {
                const float xk = (k4 == 0) ? xv[q].x : (k4 == 1) ? xv[q].y
                               : (k4 == 2) ? xv[q].z : xv[q].w;
                const float4* wr = (const float4*)(&sW[c * 16 + q * 4 + k4][0]);
#pragma unroll
                for (int jj = 0; jj < 16; ++jj) {
                    const float4 w = wr[jj];
                    h[jj].x = fmaf(xk, w.x, h[jj].x);
                    h[jj].y = fmaf(xk, w.y, h[jj].y);
                    h[jj].z = fmaf(xk, w.z, h[jj].z);
                    h[jj].w = fmaf(xk, w.w, h[jj].w);
                }
            }
        }
    }

    // ---- t = h @ W1 + b1  (64x32) ----
    float4 t[8];
#pragma unroll
    for (int jj = 0; jj < 8; ++jj) t[jj] = ((const float4*)sb1)[jj];
#pragma unroll
    for (int kk = 0; kk < 16; ++kk) {
#pragma unroll
        for (int k4 = 0; k4 < 4; ++k4) {
            const float hk = (k4 == 0) ? h[kk].x : (k4 == 1) ? h[kk].y
                           : (k4 == 2) ? h[kk].z : h[kk].w;
            const float4* wr = (const float4*)(&sW1[kk * 4 + k4][0]);
#pragma unroll
            for (int jj = 0; jj < 8; ++jj) {
                const float4 w = wr[jj];
                t[jj].x = fmaf(hk, w.x, t[jj].x);
                t[jj].y = fmaf(hk, w.y, t[jj].y);
                t[jj].z = fmaf(hk, w.z, t[jj].z);
                t[jj].w = fmaf(hk, w.w, t[jj].w);
            }
        }
    }

    // ---- p = gelu(t) @ W2 + b2 ; peak = sigmoid(p) ----
    float p = sb2;
#pragma unroll
    for (int jj = 0; jj < 8; ++jj) {
        const float4 tv = t[jj];
        const float4 w2 = ((const float4*)sW2)[jj];
        p = fmaf(gelu_exact(tv.x), w2.x, p);
        p = fmaf(gelu_exact(tv.y), w2.y, p);
        p = fmaf(gelu_exact(tv.z), w2.z, p);
        p = fmaf(gelu_exact(tv.w), w2.w, p);
    }
    const float peak = 1.0f / (1.0f + expf(-p));
    const float scale = (flag[i] != 0) ? (1.0f + peak) : 0.0f;

    // ---- out = h*scale + bias ----
    float4* outr = (float4*)(out + (size_t)i * D);
#pragma unroll
    for (int jj = 0; jj < 16; ++jj) {
        const float4 hv = h[jj];
        const float4 bv = ((const float4*)sbias)[jj];
        float4 o;
        o.x = fmaf(hv.x, scale, bv.x);
        o.y = fmaf(hv.y, scale, bv.y);
        o.z = fmaf(hv.z, scale, bv.z);
        o.w = fmaf(hv.w, scale, bv.w);
        outr[jj] = o;
    }
}

extern "C" void kernel_launch(void* const* d_in, const int* in_sizes, int n_in,
                              void* d_out, int out_size, void* d_ws, size_t ws_size,
                              hipStream_t stream) {
    const float* x    = (const float*)d_in[0];
    const int*   eidx = (const int*)d_in[1];   // [2, E] row-major: first E = row
    const float* Wlin = (const float*)d_in[2];
    // d_in[3] att_src, d_in[4] att_dst: mathematically cancel (softmax sums to 1)
    const float* bias = (const float*)d_in[5];
    const float* W1   = (const float*)d_in[6];
    const float* b1   = (const float*)d_in[7];
    const float* W2   = (const float*)d_in[8];
    const float* b2   = (const float*)d_in[9];
    float* out = (float*)d_out;

    const int N = in_sizes[0] / D;
    const int E = in_sizes[1] / 2;

    int* flag = (int*)d_ws;
    hipMemsetAsync(flag, 0, (size_t)N * sizeof(int), stream);
    edge_flag_kernel<<<(E + 255) / 256, 256, 0, stream>>>(eidx, flag, E);
    gat_fused<<<(N + 127) / 128, 128, 0, stream>>>(x, Wlin, bias, W1, b1, W2, b2, flag, out, N);
}

// Round 2
// 54.783 us; speedup vs baseline: 22.3219x; 22.3219x over previous
//
#include <hip/hip_runtime.h>
#include <math.h>

#define D 64
#define DH 32
#define NPB 64          // nodes per block
#define TPB 256         // 4 threads per node

// ---------------------------------------------------------------------------
// Softmax over each row-segment sums to exactly 1, so
//   out[i] = has_edge(i) ? h[i]*(1+peak[i]) + bias : bias
// att_src/att_dst/leaky-relu/segment-softmax cancel analytically.
// ---------------------------------------------------------------------------
__global__ void edge_flag_kernel(const int* __restrict__ row, int* __restrict__ flag, int E) {
    int e = blockIdx.x * blockDim.x + threadIdx.x;
    if (e < E) flag[row[e]] = 1;
}

__device__ __forceinline__ float gelu_exact(float v) {
    return 0.5f * v * (1.0f + erff(v * 0.70710678118654752f));
}

// 64 nodes per 256-thread block; thread (n = tid>>2, p = tid&3) owns outputs
// [p*16, p*16+16) of node n. x/h rows shared via padded LDS tile (reused).
__global__ __launch_bounds__(TPB) void gat_fused2(
    const float* __restrict__ x, const float* __restrict__ Wlin,
    const float* __restrict__ bias, const float* __restrict__ W1,
    const float* __restrict__ b1, const float* __restrict__ W2,
    const float* __restrict__ b2, const int* __restrict__ flag,
    float* __restrict__ out, int N)
{
    __shared__ float sW[D][D];        // 16 KB
    __shared__ float sW1[D][DH];      // 8 KB
    __shared__ float sX[NPB][D + 4];  // 17 KB, pad 4 floats; reused for h
    __shared__ float sb1[DH], sW2[DH], sbias[D];
    __shared__ float sb2;

    const int tid  = threadIdx.x;
    const int base = blockIdx.x * NPB;

    // ---- stage weights (coalesced float4) ----
    {
        float4* dW = (float4*)&sW[0][0];
        const float4* gW = (const float4*)Wlin;
        for (int idx = tid; idx < D * D / 4; idx += TPB) dW[idx] = gW[idx];
        float4* dW1 = (float4*)&sW1[0][0];
        const float4* gW1 = (const float4*)W1;
        for (int idx = tid; idx < D * DH / 4; idx += TPB) dW1[idx] = gW1[idx];
        if (tid < DH) { sb1[tid] = b1[tid]; sW2[tid] = W2[tid]; }
        if (tid >= 64 && tid < 128) sbias[tid - 64] = bias[tid - 64];
        if (tid == 128) sb2 = b2[0];
    }
    // ---- stage x tile (coalesced float4; 64B/lane lines fully used) ----
    {
        const float4* gx = (const float4*)(x + (size_t)base * D);
        for (int idx = tid; idx < NPB * (D / 4); idx += TPB) {
            const int r = idx >> 4, c = idx & 15;
            if (base + r < N) *(float4*)&sX[r][c * 4] = gx[idx];
        }
    }
    __syncthreads();

    const int n   = tid >> 2;
    const int p   = tid & 3;
    const int p16 = p * 16;
    const bool valid = (base + n) < N;

    // ---- h[n, p16..p16+16) = x[n,:] @ W[:, p16..p16+16) ----
    float4 a0 = make_float4(0.f,0.f,0.f,0.f), a1 = a0, a2 = a0, a3 = a0;
    {
        const float* xrow = &sX[n][0];
#pragma unroll 8
        for (int k = 0; k < D; ++k) {
            const float xk = xrow[k];
            const float4* wr = (const float4*)&sW[k][p16];
            const float4 w0 = wr[0], w1 = wr[1], w2v = wr[2], w3 = wr[3];
            a0.x = fmaf(xk, w0.x, a0.x); a0.y = fmaf(xk, w0.y, a0.y);
            a0.z = fmaf(xk, w0.z, a0.z); a0.w = fmaf(xk, w0.w, a0.w);
            a1.x = fmaf(xk, w1.x, a1.x); a1.y = fmaf(xk, w1.y, a1.y);
            a1.z = fmaf(xk, w1.z, a1.z); a1.w = fmaf(xk, w1.w, a1.w);
            a2.x = fmaf(xk, w2v.x, a2.x); a2.y = fmaf(xk, w2v.y, a2.y);
            a2.z = fmaf(xk, w2v.z, a2.z); a2.w = fmaf(xk, w2v.w, a2.w);
            a3.x = fmaf(xk, w3.x, a3.x); a3.y = fmaf(xk, w3.y, a3.y);
            a3.z = fmaf(xk, w3.z, a3.z); a3.w = fmaf(xk, w3.w, a3.w);
        }
    }
    __syncthreads();   // all x reads done -> safe to overwrite tile with h
    *(float4*)&sX[n][p16 + 0]  = a0;
    *(float4*)&sX[n][p16 + 4]  = a1;
    *(float4*)&sX[n][p16 + 8]  = a2;
    *(float4*)&sX[n][p16 + 12] = a3;
    __syncthreads();

    // ---- t[n, p*8..p*8+8) = h[n,:] @ W1[:, p*8..) + b1 ----
    float4 t0 = ((const float4*)sb1)[p * 2 + 0];
    float4 t1 = ((const float4*)sb1)[p * 2 + 1];
    {
        const float* hrow = &sX[n][0];
#pragma unroll 8
        for (int k = 0; k < D; ++k) {
            const float hk = hrow[k];
            const float4* wr = (const float4*)&sW1[k][p * 8];
            const float4 w0 = wr[0], w1 = wr[1];
            t0.x = fmaf(hk, w0.x, t0.x); t0.y = fmaf(hk, w0.y, t0.y);
            t0.z = fmaf(hk, w0.z, t0.z); t0.w = fmaf(hk, w0.w, t0.w);
            t1.x = fmaf(hk, w1.x, t1.x); t1.y = fmaf(hk, w1.y, t1.y);
            t1.z = fmaf(hk, w1.z, t1.z); t1.w = fmaf(hk, w1.w, t1.w);
        }
    }

    // ---- partial peak dot + 4-lane butterfly reduce ----
    float pp = 0.f;
    {
        const float4 u0 = ((const float4*)sW2)[p * 2 + 0];
        const float4 u1 = ((const float4*)sW2)[p * 2 + 1];
        pp = fmaf(gelu_exact(t0.x), u0.x, pp);
        pp = fmaf(gelu_exact(t0.y), u0.y, pp);
        pp = fmaf(gelu_exact(t0.z), u0.z, pp);
        pp = fmaf(gelu_exact(t0.w), u0.w, pp);
        pp = fmaf(gelu_exact(t1.x), u1.x, pp);
        pp = fmaf(gelu_exact(t1.y), u1.y, pp);
        pp = fmaf(gelu_exact(t1.z), u1.z, pp);
        pp = fmaf(gelu_exact(t1.w), u1.w, pp);
    }
    pp += __shfl_xor(pp, 1);
    pp += __shfl_xor(pp, 2);

    float scale = 0.f;
    if (valid && flag[base + n] != 0) {
        const float ptot = pp + sb2;
        scale = 1.f + 1.f / (1.f + expf(-ptot));   // 1 + sigmoid
    }

    // ---- out = h*scale + bias (coalesced float4 stores) ----
    if (valid) {
        float4* outr = (float4*)(out + (size_t)(base + n) * D + p16);
        const float4* bv = (const float4*)&sbias[p16];
        const float4 h4[4] = {a0, a1, a2, a3};
#pragma unroll
        for (int jj = 0; jj < 4; ++jj) {
            const float4 hv = h4[jj], b4 = bv[jj];
            float4 o;
            o.x = fmaf(hv.x, scale, b4.x);
            o.y = fmaf(hv.y, scale, b4.y);
            o.z = fmaf(hv.z, scale, b4.z);
            o.w = fmaf(hv.w, scale, b4.w);
            outr[jj] = o;
        }
    }
}

extern "C" void kernel_launch(void* const* d_in, const int* in_sizes, int n_in,
                              void* d_out, int out_size, void* d_ws, size_t ws_size,
                              hipStream_t stream) {
    const float* x    = (const float*)d_in[0];
    const int*   eidx = (const int*)d_in[1];   // [2, E]: first E entries = row
    const float* Wlin = (const float*)d_in[2];
    // d_in[3] att_src, d_in[4] att_dst cancel (segment softmax sums to 1)
    const float* bias = (const float*)d_in[5];
    const float* W1   = (const float*)d_in[6];
    const float* b1   = (const float*)d_in[7];
    const float* W2   = (const float*)d_in[8];
    const float* b2   = (const float*)d_in[9];
    float* out = (float*)d_out;

    const int N = in_sizes[0] / D;
    const int E = in_sizes[1] / 2;

    int* flag = (int*)d_ws;
    hipMemsetAsync(flag, 0, (size_t)N * sizeof(int), stream);
    edge_flag_kernel<<<(E + 255) / 256, 256, 0, stream>>>(eidx, flag, E);
    gat_fused2<<<(N + NPB - 1) / NPB, TPB, 0, stream>>>(x, Wlin, bias, W1, b1, W2, b2,
                                                        flag, out, N);
}